// Round 5
// baseline (365.497 us; speedup 1.0000x reference)
//
#include <hip/hip_runtime.h>
#include <math.h>

// ---------------- constant tables ----------------
__constant__ int G_ORD[17] = {0,1,2,3,4,5,6, 10,11,12,13, 7,8,9, 14,15, 16};
__constant__ int G_WA[17]  = {0,2,4,6,1,3,5, 1,3,5,7, 0,4,2, 2,6, 0};
__constant__ int G_WB[17]  = {1,3,5,7,2,4,6, 0,2,4,6, 2,6,4, 0,4, 4};
__constant__ int CDESC[10][3] = {{0,0,1},{0,2,3},{0,4,5},{0,6,7},{0,1,2},{0,3,4},{0,5,6},
                                 {1,0,1},{1,2,3},{1,1,2}};
__constant__ int PDESC[6][2] = {{0,0},{0,1},{0,2},{0,3},{1,0},{1,1}};
__constant__ float2 PMAT[4][4] = {
  {{1.f,0.f},{0.f,0.f},{0.f,0.f},{1.f,0.f}},
  {{0.f,0.f},{1.f,0.f},{1.f,0.f},{0.f,0.f}},
  {{0.f,0.f},{0.f,-1.f},{0.f,1.f},{0.f,0.f}},
  {{1.f,0.f},{0.f,0.f},{0.f,0.f},{-1.f,0.f}}};

__device__ __forceinline__ float2 cmul(float2 a, float2 b){
  return make_float2(a.x*b.x - a.y*b.y, a.x*b.y + a.y*b.x);
}
__device__ __forceinline__ float2 cadd(float2 a, float2 b){
  return make_float2(a.x+b.x, a.y+b.y);
}

__device__ void u3m(float t, float p, float d, float2* u){
  float ct = cosf(0.5f*t), st = sinf(0.5f*t);
  u[0] = make_float2(ct, 0.f);
  u[1] = make_float2(-cosf(d)*st, -sinf(d)*st);
  u[2] = make_float2(cosf(p)*st,  sinf(p)*st);
  u[3] = make_float2(cosf(p+d)*ct, sinf(p+d)*ct);
}

__device__ void kron2(const float2* A, const float2* B, float2* M){
  #pragma unroll
  for (int ia=0; ia<2; ia++)
    #pragma unroll
    for (int ib=0; ib<2; ib++)
      #pragma unroll
      for (int ja=0; ja<2; ja++)
        #pragma unroll
        for (int jb=0; jb<2; jb++)
          M[(ia*2+ib)*4 + (ja*2+jb)] = cmul(A[ia*2+ja], B[ib*2+jb]);
}

__device__ void mul44(const float2* A, const float2* B, float2* C){
  #pragma unroll
  for (int r=0;r<4;r++)
    #pragma unroll
    for (int c=0;c<4;c++){
      float2 s = make_float2(0.f,0.f);
      #pragma unroll
      for (int k=0;k<4;k++) s = cadd(s, cmul(A[r*4+k], B[k*4+c]));
      C[r*4+c] = s;
    }
}

__device__ void rotword(float phi, int qa, int qb, float2* R){
  float ch = cosf(0.5f*phi), sh = sinf(0.5f*phi);
  float2 W[16];
  kron2(PMAT[qa], PMAT[qb], W);
  #pragma unroll
  for (int i=0;i<16;i++) R[i] = make_float2(sh*W[i].y, -sh*W[i].x);
  #pragma unroll
  for (int d=0;d<4;d++) R[d*4+d].x += ch;
}

// ---------------- kernel 1: gates (redundant per block, in LDS) + U columns ----------------
__global__ __launch_bounds__(64) void build_u_kernel(
    const float* __restrict__ conv, const float* __restrict__ pool,
    const float* __restrict__ last, float2* __restrict__ U){
  __shared__ float2 gl[17][16];
  __shared__ float2 st[256];
  int t = threadIdx.x, col = blockIdx.x;
  {
    float2 M[16], T[16], R[16];
    if (t < 10){
      int layer = CDESC[t][0], ra = CDESC[t][1], rb = CDESC[t][2];
      const float* cw = conv + layer*120;
      int bA = ra*15, bB = rb*15;
      float2 A1[4], B1[4], A2[4], B2[4], K[16];
      u3m(cw[bA+0], cw[bA+1], cw[bA+2], A1);
      u3m(cw[bB+3], cw[bB+4], cw[bB+5], B1);
      kron2(A1, B1, M);
      rotword(cw[bA+6], 3, 3, R); mul44(R, M, T);   // ZZ
      rotword(cw[bA+7], 2, 2, R); mul44(R, T, M);   // YY
      rotword(cw[bA+8], 1, 1, R); mul44(R, M, T);   // XX
      u3m(cw[bA+9],  cw[bA+10], cw[bA+11], A2);
      u3m(cw[bB+12], cw[bB+13], cw[bB+14], B2);
      kron2(A2, B2, K); mul44(K, T, M);
    } else if (t < 16){
      int layer = PDESC[t-10][0], h = PDESC[t-10][1];
      const float* pw = pool + layer*12 + h*3;
      float2 u[4];
      u3m(pw[0], pw[1], pw[2], u);
      #pragma unroll
      for (int i=0;i<16;i++) M[i] = make_float2(0.f,0.f);
      M[0]  = make_float2(1.f,0.f);
      M[5]  = make_float2(1.f,0.f);
      M[10] = u[0]; M[11] = u[1]; M[14] = u[2]; M[15] = u[3];
    } else if (t == 16){
      #pragma unroll
      for (int i=0;i<16;i++) M[i] = make_float2((i%5==0)?1.f:0.f, 0.f);
      for (int k=0;k<15;k++){
        int w = k+1;
        rotword(last[k], w>>2, w&3, R);
        mul44(R, M, T);
        #pragma unroll
        for (int i=0;i<16;i++) M[i] = T[i];
      }
    }
    if (t < 17){
      #pragma unroll
      for (int i=0;i<16;i++) gl[t][i] = M[i];
    }
  }
  #pragma unroll
  for (int k=t; k<256; k+=64) st[k] = make_float2(k==col ? 1.f : 0.f, 0.f);
  __syncthreads();
  for (int g=0; g<17; g++){
    int slot = G_ORD[g];
    float2 m[16];
    #pragma unroll
    for (int i=0;i<16;i++) m[i] = gl[slot][i];
    int pa = 7 - G_WA[g], pb = 7 - G_WB[g];
    int plo = pa < pb ? pa : pb, phi_ = pa < pb ? pb : pa;
    int mm = t;
    int t1   = ((mm >> plo) << (plo+1)) | (mm & ((1<<plo)-1));
    int base = ((t1 >> phi_) << (phi_+1)) | (t1 & ((1<<phi_)-1));
    int ba = 1<<pa, bb = 1<<pb;
    int i0 = base, i1 = base|bb, i2 = base|ba, i3 = base|ba|bb;
    float2 s0 = st[i0], s1 = st[i1], s2 = st[i2], s3 = st[i3];
    float2 n0 = cadd(cadd(cmul(m[0], s0), cmul(m[1], s1)), cadd(cmul(m[2], s2), cmul(m[3], s3)));
    float2 n1 = cadd(cadd(cmul(m[4], s0), cmul(m[5], s1)), cadd(cmul(m[6], s2), cmul(m[7], s3)));
    float2 n2 = cadd(cadd(cmul(m[8], s0), cmul(m[9], s1)), cadd(cmul(m[10],s2), cmul(m[11],s3)));
    float2 n3 = cadd(cadd(cmul(m[12],s0), cmul(m[13],s1)), cadd(cmul(m[14],s2), cmul(m[15],s3)));
    st[i0] = n0; st[i1] = n1; st[i2] = n2; st[i3] = n3;
    __syncthreads();
  }
  #pragma unroll
  for (int k=t; k<256; k+=64) U[k*256 + col] = st[k];
}

// ---------------- kernel 2: A[i][j] = sum_k sgn_k Re(conj(U_ki) U_kj) ----------------
__global__ __launch_bounds__(256) void build_a_kernel(
    const float2* __restrict__ U, float* __restrict__ A){
  int j = threadIdx.x, i0 = blockIdx.x*2;
  float a0=0.f, a1=0.f;
  #pragma unroll 8
  for (int k=0; k<256; k++){
    float2 uj = U[k*256 + j];
    float2 u0 = U[k*256 + i0+0];
    float2 u1 = U[k*256 + i0+1];
    float sgn = (k < 128) ? 1.f : -1.f;   // qubit0 = bit7 (MSB), Z eigenvalue
    a0 += sgn*(u0.x*uj.x + u0.y*uj.y);
    a1 += sgn*(u1.x*uj.x + u1.y*uj.y);
  }
  A[(i0+0)*256 + j] = a0;
  A[(i0+1)*256 + j] = a1;
}

// ---------------- kernel 3: fused feats + psi + q=psi^T A psi + logits ----------------
// 512 blocks x 512 threads (8 waves), 16 rows/block, 2 blocks/CU -> 16 waves/CU (50%).
// Phase F: wave wv owns rows r0+wv*2..+1, streams x with float4, weights from L2.
// Phase Q: wave wv owns k-chunk [wv*32, wv*32+32) of A, read DIRECTLY from global
//   (A = 256KB, L2-resident; no LDS staging, no inner syncthreads). Lane jb owns
//   4 columns; acc4[16] covers all 16 rows. Cross-wave reduce via tiny LDS buffer.
__global__ __launch_bounds__(512, 4) void main_kernel(
    const float* __restrict__ x, const float* __restrict__ fcw,
    const float* __restrict__ fcb, const float* __restrict__ Ag,
    const float* __restrict__ outw, const float* __restrict__ outb,
    float* __restrict__ out){
  __shared__ float lds[8704];         // union: red 128x68 (34.8KB) | ps 16x256 (16KB)
  __shared__ float flds[128];         // 16 rows x 8 feats
  __shared__ float qpart[8][16];      // per-wave partial q
  float* red = lds;
  float* ps  = lds;
  int t = threadIdx.x, lane = t & 63, wv = t >> 6, jb = lane;
  int r0 = blockIdx.x * 16;
  // ---- phase F: per-wave GEMM over k=3072 (12 passes of float4), 2 rows/wave ----
  {
    int rw = r0 + wv*2;
    const float4* x4 = (const float4*)x;
    const float4* w4 = (const float4*)fcw;
    float acc[2][8];
    #pragma unroll
    for (int r=0;r<2;r++)
      #pragma unroll
      for (int o=0;o<8;o++) acc[r][o] = 0.f;
    #pragma unroll 2
    for (int p=0; p<12; p++){
      float4 wf[8];
      #pragma unroll
      for (int o=0;o<8;o++) wf[o] = w4[o*768 + p*64 + lane];
      #pragma unroll
      for (int r=0;r<2;r++){
        float4 xv = x4[(size_t)(rw+r)*768 + p*64 + lane];
        #pragma unroll
        for (int o=0;o<8;o++){
          acc[r][o] += xv.x*wf[o].x + xv.y*wf[o].y + xv.z*wf[o].z + xv.w*wf[o].w;
        }
      }
    }
    #pragma unroll
    for (int r=0;r<2;r++)
      #pragma unroll
      for (int o=0;o<8;o++)
        red[((wv*2+r)*8 + o)*68 + lane] = acc[r][o];
  }
  __syncthreads();
  // ---- phase R: LDS-transpose reduce + tanh -> flds ----
  if (t < 128){
    const float4* rp = (const float4*)(red + t*68);
    float4 s4 = make_float4(0.f,0.f,0.f,0.f);
    #pragma unroll
    for (int i=0;i<16;i++){
      float4 v = rp[i];
      s4.x += v.x; s4.y += v.y; s4.z += v.z; s4.w += v.w;
    }
    flds[t] = tanhf(s4.x + s4.y + s4.z + s4.w + fcb[t & 7]);
  }
  __syncthreads();   // red fully read; flds ready
  // ---- phase P: build psi rows in ps (aliases red; safe after sync) ----
  if (t < 256){
    int row = t >> 4, i1 = t & 15;
    const float* f = flds + row*8;
    float c[8], s[8];
    #pragma unroll
    for (int w=0; w<8; w++){
      float a = 0.5f*f[w];
      __sincosf(a, &s[w], &c[w]);
    }
    float Hv = (i1&8 ? s[0]:c[0]) * (i1&4 ? s[1]:c[1])
             * (i1&2 ? s[2]:c[2]) * (i1&1 ? s[3]:c[3]);
    float l2[2], l4[4], l8[8], L[16];
    l2[0]=c[4]; l2[1]=s[4];
    #pragma unroll
    for (int a=0;a<2;a++){ l4[a*2]=l2[a]*c[5]; l4[a*2+1]=l2[a]*s[5]; }
    #pragma unroll
    for (int a=0;a<4;a++){ l8[a*2]=l4[a]*c[6]; l8[a*2+1]=l4[a]*s[6]; }
    #pragma unroll
    for (int a=0;a<8;a++){ L[a*2]=l8[a]*c[7]; L[a*2+1]=l8[a]*s[7]; }
    float4* dst = (float4*)(ps + row*256 + i1*16);
    #pragma unroll
    for (int qd=0; qd<4; qd++)
      dst[qd] = make_float4(Hv*L[qd*4+0], Hv*L[qd*4+1], Hv*L[qd*4+2], Hv*L[qd*4+3]);
  }
  __syncthreads();
  // ---- phase Q: wave-private k-chunk of A from global; acc4[16] in registers ----
  const float4* ps4 = (const float4*)ps;
  const float4* Ag4 = (const float4*)Ag;
  float4 acc4[16];
  #pragma unroll
  for (int r=0;r<16;r++) acc4[r] = make_float4(0.f,0.f,0.f,0.f);
  #pragma unroll 2
  for (int g=0; g<8; g++){
    int k = wv*32 + g*4;
    float4 a0 = Ag4[(k+0)*64 + jb];
    float4 a1 = Ag4[(k+1)*64 + jb];
    float4 a2 = Ag4[(k+2)*64 + jb];
    float4 a3 = Ag4[(k+3)*64 + jb];
    #pragma unroll
    for (int r=0; r<16; r++){
      float4 pk = ps4[r*64 + wv*8 + g];   // wave-uniform broadcast: psi[row][k..k+3]
      acc4[r].x += pk.x*a0.x + pk.y*a1.x + pk.z*a2.x + pk.w*a3.x;
      acc4[r].y += pk.x*a0.y + pk.y*a1.y + pk.z*a2.y + pk.w*a3.y;
      acc4[r].z += pk.x*a0.z + pk.y*a1.z + pk.z*a2.z + pk.w*a3.z;
      acc4[r].w += pk.x*a0.w + pk.y*a1.w + pk.z*a2.w + pk.w*a3.w;
    }
  }
  // ---- epilogue: dot with psi columns, butterfly, cross-wave reduce ----
  #pragma unroll
  for (int r=0; r<16; r++){
    float4 pc = ps4[r*64 + jb];
    float q = acc4[r].x*pc.x + acc4[r].y*pc.y + acc4[r].z*pc.z + acc4[r].w*pc.w;
    #pragma unroll
    for (int m=1; m<64; m<<=1) q += __shfl_xor(q, m, 64);
    if (lane == 0) qpart[wv][r] = q;
  }
  __syncthreads();
  if (t < 160){
    int row = t / 10, c = t - row*10;
    float q = 0.f;
    #pragma unroll
    for (int w=0; w<8; w++) q += qpart[w][row];
    out[(r0 + row)*10 + c] = q*outw[c] + outb[c];
  }
}

// ---------------- launch ----------------
extern "C" void kernel_launch(void* const* d_in, const int* in_sizes, int n_in,
                              void* d_out, int out_size, void* d_ws, size_t ws_size,
                              hipStream_t stream) {
  const float* x    = (const float*)d_in[0];
  const float* fcw  = (const float*)d_in[1];
  const float* fcb  = (const float*)d_in[2];
  const float* conv = (const float*)d_in[3];
  const float* pool = (const float*)d_in[4];
  const float* last = (const float*)d_in[5];
  const float* outw = (const float*)d_in[6];
  const float* outb = (const float*)d_in[7];
  float* out = (float*)d_out;

  float* ws = (float*)d_ws;
  float2* U  = (float2*)ws;            // 256*256 complex = 131072 floats
  float*  Am = ws + 131072;            // 65536 floats

  build_u_kernel<<<256, 64, 0, stream>>>(conv, pool, last, U);
  build_a_kernel<<<128, 256, 0, stream>>>(U, Am);
  main_kernel<<<512, 512, 0, stream>>>(x, fcw, fcb, Am, outw, outb, out);
}

// Round 6
// 246.521 us; speedup vs baseline: 1.4826x; 1.4826x over previous
//
#include <hip/hip_runtime.h>
#include <math.h>

// ---------------- constant tables ----------------
__constant__ int G_ORD[17] = {0,1,2,3,4,5,6, 10,11,12,13, 7,8,9, 14,15, 16};
__constant__ int G_WA[17]  = {0,2,4,6,1,3,5, 1,3,5,7, 0,4,2, 2,6, 0};
__constant__ int G_WB[17]  = {1,3,5,7,2,4,6, 0,2,4,6, 2,6,4, 0,4, 4};
__constant__ int CDESC[10][3] = {{0,0,1},{0,2,3},{0,4,5},{0,6,7},{0,1,2},{0,3,4},{0,5,6},
                                 {1,0,1},{1,2,3},{1,1,2}};
__constant__ int PDESC[6][2] = {{0,0},{0,1},{0,2},{0,3},{1,0},{1,1}};
__constant__ float2 PMAT[4][4] = {
  {{1.f,0.f},{0.f,0.f},{0.f,0.f},{1.f,0.f}},
  {{0.f,0.f},{1.f,0.f},{1.f,0.f},{0.f,0.f}},
  {{0.f,0.f},{0.f,-1.f},{0.f,1.f},{0.f,0.f}},
  {{1.f,0.f},{0.f,0.f},{0.f,0.f},{-1.f,0.f}}};

__device__ __forceinline__ float2 cmul(float2 a, float2 b){
  return make_float2(a.x*b.x - a.y*b.y, a.x*b.y + a.y*b.x);
}
__device__ __forceinline__ float2 cadd(float2 a, float2 b){
  return make_float2(a.x+b.x, a.y+b.y);
}
__device__ __forceinline__ float rl(float v, int l){
  return __int_as_float(__builtin_amdgcn_readlane(__float_as_int(v), l));
}

__device__ void u3m(float t, float p, float d, float2* u){
  float ct = cosf(0.5f*t), st = sinf(0.5f*t);
  u[0] = make_float2(ct, 0.f);
  u[1] = make_float2(-cosf(d)*st, -sinf(d)*st);
  u[2] = make_float2(cosf(p)*st,  sinf(p)*st);
  u[3] = make_float2(cosf(p+d)*ct, sinf(p+d)*ct);
}

__device__ void kron2(const float2* A, const float2* B, float2* M){
  #pragma unroll
  for (int ia=0; ia<2; ia++)
    #pragma unroll
    for (int ib=0; ib<2; ib++)
      #pragma unroll
      for (int ja=0; ja<2; ja++)
        #pragma unroll
        for (int jb=0; jb<2; jb++)
          M[(ia*2+ib)*4 + (ja*2+jb)] = cmul(A[ia*2+ja], B[ib*2+jb]);
}

__device__ void mul44(const float2* A, const float2* B, float2* C){
  #pragma unroll
  for (int r=0;r<4;r++)
    #pragma unroll
    for (int c=0;c<4;c++){
      float2 s = make_float2(0.f,0.f);
      #pragma unroll
      for (int k=0;k<4;k++) s = cadd(s, cmul(A[r*4+k], B[k*4+c]));
      C[r*4+c] = s;
    }
}

__device__ void rotword(float phi, int qa, int qb, float2* R){
  float ch = cosf(0.5f*phi), sh = sinf(0.5f*phi);
  float2 W[16];
  kron2(PMAT[qa], PMAT[qb], W);
  #pragma unroll
  for (int i=0;i<16;i++) R[i] = make_float2(sh*W[i].y, -sh*W[i].x);
  #pragma unroll
  for (int d=0;d<4;d++) R[d*4+d].x += ch;
}

// ---------------- kernel 1: gates (redundant per block, in LDS) + U columns ----------------
__global__ __launch_bounds__(64) void build_u_kernel(
    const float* __restrict__ conv, const float* __restrict__ pool,
    const float* __restrict__ last, float2* __restrict__ U){
  __shared__ float2 gl[17][16];
  __shared__ float2 st[256];
  int t = threadIdx.x, col = blockIdx.x;
  {
    float2 M[16], T[16], R[16];
    if (t < 10){
      int layer = CDESC[t][0], ra = CDESC[t][1], rb = CDESC[t][2];
      const float* cw = conv + layer*120;
      int bA = ra*15, bB = rb*15;
      float2 A1[4], B1[4], A2[4], B2[4], K[16];
      u3m(cw[bA+0], cw[bA+1], cw[bA+2], A1);
      u3m(cw[bB+3], cw[bB+4], cw[bB+5], B1);
      kron2(A1, B1, M);
      rotword(cw[bA+6], 3, 3, R); mul44(R, M, T);   // ZZ
      rotword(cw[bA+7], 2, 2, R); mul44(R, T, M);   // YY
      rotword(cw[bA+8], 1, 1, R); mul44(R, M, T);   // XX
      u3m(cw[bA+9],  cw[bA+10], cw[bA+11], A2);
      u3m(cw[bB+12], cw[bB+13], cw[bB+14], B2);
      kron2(A2, B2, K); mul44(K, T, M);
    } else if (t < 16){
      int layer = PDESC[t-10][0], h = PDESC[t-10][1];
      const float* pw = pool + layer*12 + h*3;
      float2 u[4];
      u3m(pw[0], pw[1], pw[2], u);
      #pragma unroll
      for (int i=0;i<16;i++) M[i] = make_float2(0.f,0.f);
      M[0]  = make_float2(1.f,0.f);
      M[5]  = make_float2(1.f,0.f);
      M[10] = u[0]; M[11] = u[1]; M[14] = u[2]; M[15] = u[3];
    } else if (t == 16){
      #pragma unroll
      for (int i=0;i<16;i++) M[i] = make_float2((i%5==0)?1.f:0.f, 0.f);
      for (int k=0;k<15;k++){
        int w = k+1;
        rotword(last[k], w>>2, w&3, R);
        mul44(R, M, T);
        #pragma unroll
        for (int i=0;i<16;i++) M[i] = T[i];
      }
    }
    if (t < 17){
      #pragma unroll
      for (int i=0;i<16;i++) gl[t][i] = M[i];
    }
  }
  #pragma unroll
  for (int k=t; k<256; k+=64) st[k] = make_float2(k==col ? 1.f : 0.f, 0.f);
  __syncthreads();
  for (int g=0; g<17; g++){
    int slot = G_ORD[g];
    float2 m[16];
    #pragma unroll
    for (int i=0;i<16;i++) m[i] = gl[slot][i];
    int pa = 7 - G_WA[g], pb = 7 - G_WB[g];
    int plo = pa < pb ? pa : pb, phi_ = pa < pb ? pb : pa;
    int mm = t;
    int t1   = ((mm >> plo) << (plo+1)) | (mm & ((1<<plo)-1));
    int base = ((t1 >> phi_) << (phi_+1)) | (t1 & ((1<<phi_)-1));
    int ba = 1<<pa, bb = 1<<pb;
    int i0 = base, i1 = base|bb, i2 = base|ba, i3 = base|ba|bb;
    float2 s0 = st[i0], s1 = st[i1], s2 = st[i2], s3 = st[i3];
    float2 n0 = cadd(cadd(cmul(m[0], s0), cmul(m[1], s1)), cadd(cmul(m[2], s2), cmul(m[3], s3)));
    float2 n1 = cadd(cadd(cmul(m[4], s0), cmul(m[5], s1)), cadd(cmul(m[6], s2), cmul(m[7], s3)));
    float2 n2 = cadd(cadd(cmul(m[8], s0), cmul(m[9], s1)), cadd(cmul(m[10],s2), cmul(m[11],s3)));
    float2 n3 = cadd(cadd(cmul(m[12],s0), cmul(m[13],s1)), cadd(cmul(m[14],s2), cmul(m[15],s3)));
    st[i0] = n0; st[i1] = n1; st[i2] = n2; st[i3] = n3;
    __syncthreads();
  }
  #pragma unroll
  for (int k=t; k<256; k+=64) U[k*256 + col] = st[k];
}

// ---------------- kernel 2: A[i][j] = sum_k sgn_k Re(conj(U_ki) U_kj) ----------------
__global__ __launch_bounds__(256) void build_a_kernel(
    const float2* __restrict__ U, float* __restrict__ A){
  int j = threadIdx.x, i0 = blockIdx.x*2;
  float a0=0.f, a1=0.f;
  #pragma unroll 8
  for (int k=0; k<256; k++){
    float2 uj = U[k*256 + j];
    float2 u0 = U[k*256 + i0+0];
    float2 u1 = U[k*256 + i0+1];
    float sgn = (k < 128) ? 1.f : -1.f;   // qubit0 = bit7 (MSB), Z eigenvalue
    a0 += sgn*(u0.x*uj.x + u0.y*uj.y);
    a1 += sgn*(u1.x*uj.x + u1.y*uj.y);
  }
  A[(i0+0)*256 + j] = a0;
  A[(i0+1)*256 + j] = a1;
}

// ---------------- kernel 3: fused feats + psi + q=psi^T A psi + logits ----------------
// 1024 blocks x 256 threads (4 waves), 8 rows/block -> 4 blocks/CU, 16 waves/CU (50%).
// Phase F: wave owns 2 rows, float4 stream of x (HBM-bound ~16us).
// Phase Q: NO LDS for A or psi-broadcast:
//   - wave wv owns k-chunk [wv*64, wv*64+64); lane jb owns cols 4jb..4jb+3;
//   - A read straight from L2, coalesced float4 (per-CU ~1MB, ~4us, overlapped);
//   - psi[r][k] broadcast via v_readlane from psiK[r] (VALU, zero LDS traffic);
//   - acc4[8] = 32 VGPRs, fits the 128-VGPR/4-wave cap WITHOUT spill (round-5 fix).
__global__ __launch_bounds__(256, 4) void main_kernel(
    const float* __restrict__ x, const float* __restrict__ fcw,
    const float* __restrict__ fcb, const float* __restrict__ Ag,
    const float* __restrict__ outw, const float* __restrict__ outb,
    float* __restrict__ out){
  __shared__ float lds[4352];         // union: red 64x68 (17.4KB) | ps 8x256 (8KB)
  __shared__ float flds[64];          // 8 rows x 8 feats
  __shared__ float qpart[4][8];       // per-wave partial q
  float* red = lds;
  float* ps  = lds;
  int t = threadIdx.x, lane = t & 63, wv = t >> 6, jb = lane;
  int r0 = blockIdx.x * 8;
  // ---- phase F: per-wave GEMM over k=3072 (12 passes of float4), 2 rows/wave ----
  {
    int rw = r0 + wv*2;
    const float4* x4 = (const float4*)x;
    const float4* w4 = (const float4*)fcw;
    float acc[2][8];
    #pragma unroll
    for (int r=0;r<2;r++)
      #pragma unroll
      for (int o=0;o<8;o++) acc[r][o] = 0.f;
    #pragma unroll 2
    for (int p=0; p<12; p++){
      float4 wf[8];
      #pragma unroll
      for (int o=0;o<8;o++) wf[o] = w4[o*768 + p*64 + lane];
      #pragma unroll
      for (int r=0;r<2;r++){
        float4 xv = x4[(size_t)(rw+r)*768 + p*64 + lane];
        #pragma unroll
        for (int o=0;o<8;o++){
          acc[r][o] += xv.x*wf[o].x + xv.y*wf[o].y + xv.z*wf[o].z + xv.w*wf[o].w;
        }
      }
    }
    #pragma unroll
    for (int r=0;r<2;r++)
      #pragma unroll
      for (int o=0;o<8;o++)
        red[((wv*2+r)*8 + o)*68 + lane] = acc[r][o];
  }
  __syncthreads();
  // ---- phase R: LDS-transpose reduce + tanh -> flds (64 sums) ----
  if (t < 64){
    const float4* rp = (const float4*)(red + t*68);
    float4 s4 = make_float4(0.f,0.f,0.f,0.f);
    #pragma unroll
    for (int i=0;i<16;i++){
      float4 v = rp[i];
      s4.x += v.x; s4.y += v.y; s4.z += v.z; s4.w += v.w;
    }
    flds[t] = tanhf(s4.x + s4.y + s4.z + s4.w + fcb[t & 7]);
  }
  __syncthreads();   // red fully read; flds ready
  // ---- phase P: build psi rows in ps (aliases red; safe after sync) ----
  {
    int row = t >> 5, idx = t & 31, i1 = idx & 15, jh = idx >> 4;
    const float* f = flds + row*8;
    float c[8], s[8];
    #pragma unroll
    for (int w=0; w<8; w++){
      float a = 0.5f*f[w];
      __sincosf(a, &s[w], &c[w]);
    }
    float Hv = (i1&8 ? s[0]:c[0]) * (i1&4 ? s[1]:c[1])
             * (i1&2 ? s[2]:c[2]) * (i1&1 ? s[3]:c[3]);
    float l2[2], l4[4], l8[8], L[16];
    l2[0]=c[4]; l2[1]=s[4];
    #pragma unroll
    for (int a=0;a<2;a++){ l4[a*2]=l2[a]*c[5]; l4[a*2+1]=l2[a]*s[5]; }
    #pragma unroll
    for (int a=0;a<4;a++){ l8[a*2]=l4[a]*c[6]; l8[a*2+1]=l4[a]*s[6]; }
    #pragma unroll
    for (int a=0;a<8;a++){ L[a*2]=l8[a]*c[7]; L[a*2+1]=l8[a]*s[7]; }
    float4* dst = (float4*)(ps + row*256 + i1*16 + jh*8);
    #pragma unroll
    for (int qd=0; qd<2; qd++){
      int b = jh*8 + qd*4;
      dst[qd] = make_float4(Hv*L[b+0], Hv*L[b+1], Hv*L[b+2], Hv*L[b+3]);
    }
  }
  __syncthreads();
  // ---- phase Q: wave k-chunk of A from L2; psi broadcast via readlane ----
  float psiK[8];
  #pragma unroll
  for (int r=0; r<8; r++) psiK[r] = ps[r*256 + wv*64 + lane];
  const float4* Ag4 = (const float4*)Ag;
  float4 acc4[8];
  #pragma unroll
  for (int r=0;r<8;r++) acc4[r] = make_float4(0.f,0.f,0.f,0.f);
  #pragma unroll 2
  for (int g=0; g<16; g++){
    int k0 = wv*64 + g*4;
    float4 a0 = Ag4[(size_t)(k0+0)*64 + jb];
    float4 a1 = Ag4[(size_t)(k0+1)*64 + jb];
    float4 a2 = Ag4[(size_t)(k0+2)*64 + jb];
    float4 a3 = Ag4[(size_t)(k0+3)*64 + jb];
    int l0 = g*4;
    #pragma unroll
    for (int r=0; r<8; r++){
      float p0 = rl(psiK[r], l0+0);
      float p1 = rl(psiK[r], l0+1);
      float p2 = rl(psiK[r], l0+2);
      float p3 = rl(psiK[r], l0+3);
      acc4[r].x += p0*a0.x + p1*a1.x + p2*a2.x + p3*a3.x;
      acc4[r].y += p0*a0.y + p1*a1.y + p2*a2.y + p3*a3.y;
      acc4[r].z += p0*a0.z + p1*a1.z + p2*a2.z + p3*a3.z;
      acc4[r].w += p0*a0.w + p1*a1.w + p2*a2.w + p3*a3.w;
    }
  }
  // ---- epilogue: dot with psi cols, butterfly, cross-wave reduce ----
  const float4* ps4 = (const float4*)ps;
  #pragma unroll
  for (int r=0; r<8; r++){
    float4 pc = ps4[r*64 + jb];
    float q = acc4[r].x*pc.x + acc4[r].y*pc.y + acc4[r].z*pc.z + acc4[r].w*pc.w;
    #pragma unroll
    for (int m=1; m<64; m<<=1) q += __shfl_xor(q, m, 64);
    if (lane == 0) qpart[wv][r] = q;
  }
  __syncthreads();
  if (t < 80){
    int row = t / 10, c = t - row*10;
    float q = qpart[0][row] + qpart[1][row] + qpart[2][row] + qpart[3][row];
    out[(r0 + row)*10 + c] = q*outw[c] + outb[c];
  }
}

// ---------------- launch ----------------
extern "C" void kernel_launch(void* const* d_in, const int* in_sizes, int n_in,
                              void* d_out, int out_size, void* d_ws, size_t ws_size,
                              hipStream_t stream) {
  const float* x    = (const float*)d_in[0];
  const float* fcw  = (const float*)d_in[1];
  const float* fcb  = (const float*)d_in[2];
  const float* conv = (const float*)d_in[3];
  const float* pool = (const float*)d_in[4];
  const float* last = (const float*)d_in[5];
  const float* outw = (const float*)d_in[6];
  const float* outb = (const float*)d_in[7];
  float* out = (float*)d_out;

  float* ws = (float*)d_ws;
  float2* U  = (float2*)ws;            // 256*256 complex = 131072 floats
  float*  Am = ws + 131072;            // 65536 floats

  build_u_kernel<<<256, 64, 0, stream>>>(conv, pool, last, U);
  build_a_kernel<<<128, 256, 0, stream>>>(U, Am);
  main_kernel<<<1024, 256, 0, stream>>>(x, fcw, fcb, Am, outw, outb, out);
}